// Round 1
// baseline (3970.447 us; speedup 1.0000x reference)
//
#include <hip/hip_runtime.h>
#include <hip/hip_fp16.h>

#define NB 64
#define NT 512
#define ND 128
#define NH 256
#define G4 1024                 // 4*H
#define NBT (NB*NT)             // 32768
#define CSTRIDE (NBT*G4)        // 33,554,432 elements per interval component

typedef _Float16 f16x2 __attribute__((ext_vector_type(2)));

__device__ __forceinline__ float fdot2u(unsigned a, unsigned b, float c) {
#if __has_builtin(__builtin_amdgcn_fdot2)
  return __builtin_amdgcn_fdot2(__builtin_bit_cast(f16x2, a),
                                __builtin_bit_cast(f16x2, b), c, false);
#else
  __half2 A = __builtin_bit_cast(__half2, a);
  __half2 Bv = __builtin_bit_cast(__half2, b);
  return fmaf(__half2float(A.y), __half2float(Bv.y),
         fmaf(__half2float(A.x), __half2float(Bv.x), c));
#endif
}

// 8 f16 MACs per component: val += w.h, m += w.h, r += |w|.h
__device__ __forceinline__ void acc8(uint4 w, uint4 hv, uint4 hm, uint4 hr,
                                     float& av, float& am, float& ar) {
  const unsigned M = 0x7FFF7FFFu;
  av = fdot2u(w.x, hv.x, av); am = fdot2u(w.x, hm.x, am); ar = fdot2u(w.x & M, hr.x, ar);
  av = fdot2u(w.y, hv.y, av); am = fdot2u(w.y, hm.y, am); ar = fdot2u(w.y & M, hr.y, ar);
  av = fdot2u(w.z, hv.z, av); am = fdot2u(w.z, hm.z, am); ar = fdot2u(w.z & M, hr.z, ar);
  av = fdot2u(w.w, hv.w, av); am = fdot2u(w.w, hm.w, am); ar = fdot2u(w.w & M, hr.w, ar);
}

__device__ __forceinline__ float sigf(float x)  { return 1.0f / (1.0f + __expf(-x)); }
__device__ __forceinline__ float tanf_(float x) { return 1.0f - 2.0f / (__expf(2.0f * x) + 1.0f); }

// Pack W_hh [1024,256] f32 and W_ih [1024,128] f32 into f16, K-chunked layout:
// Wq[k8][j] = uint4 holding W[j][8*k8 .. 8*k8+7] as 4x half2 (wave loads 1KiB contiguous).
__global__ void conv_w_kernel(const float* __restrict__ Whh, const float* __restrict__ Wih,
                              uint4* __restrict__ WqHH, uint4* __restrict__ WqIH) {
  int tid = blockIdx.x * 256 + threadIdx.x;
  union { uint4 u; __half h[8]; } p;
  if (tid < 32 * 1024) {                       // W_hh: 32 k8-chunks x 1024 rows
    int k8 = tid >> 10, j = tid & 1023;
    const float* s = Whh + j * NH + k8 * 8;
#pragma unroll
    for (int i = 0; i < 8; ++i) p.h[i] = __float2half(s[i]);
    WqHH[tid] = p.u;
  } else if (tid < 48 * 1024) {                // W_ih: 16 k8-chunks x 1024 rows
    int t2 = tid - 32 * 1024;
    int k8 = t2 >> 10, j = t2 & 1023;
    const float* s = Wih + j * ND + k8 * 8;
#pragma unroll
    for (int i = 0; i < 8; ++i) p.h[i] = __float2half(s[i]);
    WqIH[t2] = p.u;
  }
}

// px[(c, bt, j)] = interval-linear of x with W_ih (no bias), f16 output.
// Block: 32 bt-rows x all 1024 j. 512 threads, thread owns rows (j, j+512) in VGPRs.
__global__ __launch_bounds__(512, 2)
void px_kernel(const float* __restrict__ xv, const float* __restrict__ xl,
               const float* __restrict__ xu, const uint4* __restrict__ WqIH,
               __half* __restrict__ px) {
  __shared__ __align__(16) __half sv[32 * ND];
  __shared__ __align__(16) __half sm[32 * ND];
  __shared__ __align__(16) __half sr[32 * ND];
  const int tid = threadIdx.x;
  const int r0 = blockIdx.x * 32;
  const int j0 = tid, j1 = tid + 512;
  uint4 w0[16], w1[16];
#pragma unroll
  for (int k = 0; k < 16; ++k) { w0[k] = WqIH[k * 1024 + j0]; w1[k] = WqIH[k * 1024 + j1]; }
  {
    const float4* v4 = (const float4*)(xv + (size_t)r0 * ND);
    const float4* l4 = (const float4*)(xl + (size_t)r0 * ND);
    const float4* u4 = (const float4*)(xu + (size_t)r0 * ND);
    __half2* sv2 = (__half2*)sv; __half2* sm2 = (__half2*)sm; __half2* sr2 = (__half2*)sr;
    for (int i = tid; i < 1024; i += 512) {    // 4096 floats per tensor as float4
      float4 v = v4[i], l = l4[i], u = u4[i];
      sv2[2*i]   = __floats2half2_rn(v.x, v.y);
      sv2[2*i+1] = __floats2half2_rn(v.z, v.w);
      sm2[2*i]   = __floats2half2_rn(0.5f*(l.x+u.x), 0.5f*(l.y+u.y));
      sm2[2*i+1] = __floats2half2_rn(0.5f*(l.z+u.z), 0.5f*(l.w+u.w));
      sr2[2*i]   = __floats2half2_rn(0.5f*(u.x-l.x), 0.5f*(u.y-l.y));
      sr2[2*i+1] = __floats2half2_rn(0.5f*(u.z-l.z), 0.5f*(u.w-l.w));
    }
  }
  __syncthreads();
  for (int rr = 0; rr < 32; ++rr) {
    const uint4* hv4 = (const uint4*)(sv + rr * ND);   // LDS broadcast reads
    const uint4* hm4 = (const uint4*)(sm + rr * ND);
    const uint4* hr4 = (const uint4*)(sr + rr * ND);
    float av0=0, am0=0, ar0=0, av1=0, am1=0, ar1=0;
#pragma unroll
    for (int k = 0; k < 16; ++k) {
      uint4 hv = hv4[k], hm = hm4[k], hr = hr4[k];
      acc8(w0[k], hv, hm, hr, av0, am0, ar0);
      acc8(w1[k], hv, hm, hr, av1, am1, ar1);
    }
    int base = (r0 + rr) * G4;
    px[base + j0]             = __float2half(av0);
    px[CSTRIDE + base + j0]   = __float2half(am0 - ar0);
    px[2*CSTRIDE + base + j0] = __float2half(am0 + ar0);
    px[base + j1]             = __float2half(av1);
    px[CSTRIDE + base + j1]   = __float2half(am1 - ar1);
    px[2*CSTRIDE + base + j1] = __float2half(am1 + ar1);
  }
}

// Recurrence: one block per batch row, 512 threads, thread owns W_hh rows (j, j+512).
// Per step: f16 dot2 GEMV (h broadcast from LDS, W streamed from L2) -> activations
// -> barrier -> interval cell update on threads 0..255 -> barrier.
__global__ __launch_bounds__(512, 2)
void lstm_kernel(const uint4* __restrict__ Wq, const __half* __restrict__ px,
                 const float* __restrict__ bias, float* __restrict__ out) {
  __shared__ __align__(16) __half sHV[NH];
  __shared__ __align__(16) __half sHM[NH];
  __shared__ __align__(16) __half sHR[NH];
  __shared__ float sA[3][G4];
  __shared__ float sC[3][NH];
  const int tid = threadIdx.x;
  const int b = blockIdx.x;
  const int j0 = tid, j1 = tid + 512;
  const float b0 = bias[j0], b1 = bias[j1];
  const bool g1 = (tid < 256);                 // row1 gate: tanh (g) for tid<256 else sigmoid (o)
  if (tid < 128) { ((unsigned*)sHV)[tid] = 0u; ((unsigned*)sHM)[tid] = 0u; ((unsigned*)sHR)[tid] = 0u; }
  if (tid < 256) { sC[0][tid] = 0.f; sC[1][tid] = 0.f; sC[2][tid] = 0.f; }
  __syncthreads();
  const __half* pxb = px + (size_t)b * NT * G4;
  float* outb = out + (size_t)b * NT * NH;
  for (int t = 0; t < NT; ++t) {
    const __half* pxt = pxb + t * G4;
    float pv0 = __half2float(pxt[j0]);
    float pl0 = __half2float(pxt[CSTRIDE + j0]);
    float pu0 = __half2float(pxt[2*CSTRIDE + j0]);
    float pv1 = __half2float(pxt[j1]);
    float pl1 = __half2float(pxt[CSTRIDE + j1]);
    float pu1 = __half2float(pxt[2*CSTRIDE + j1]);
    float av0=0, am0=0, ar0=0, av1=0, am1=0, ar1=0;
    const uint4* hv4 = (const uint4*)sHV;
    const uint4* hm4 = (const uint4*)sHM;
    const uint4* hr4 = (const uint4*)sHR;
#pragma unroll 8
    for (int k = 0; k < 32; ++k) {
      uint4 hv = hv4[k], hm = hm4[k], hr = hr4[k];  // same addr all lanes: broadcast
      uint4 w0 = Wq[k * 1024 + j0];                 // 1KiB/wave contiguous from L2
      uint4 w1 = Wq[k * 1024 + j1];
      acc8(w0, hv, hm, hr, av0, am0, ar0);
      acc8(w1, hv, hm, hr, av1, am1, ar1);
    }
    float qv0 = pv0 + b0 + av0;
    float ql0 = pl0 + b0 + (am0 - ar0);
    float qu0 = pu0 + b0 + (am0 + ar0);
    float qv1 = pv1 + b1 + av1;
    float ql1 = pl1 + b1 + (am1 - ar1);
    float qu1 = pu1 + b1 + (am1 + ar1);
    sA[0][j0] = sigf(qv0); sA[1][j0] = sigf(ql0); sA[2][j0] = sigf(qu0);  // i/f: sigmoid
    if (g1) { sA[0][j1] = tanf_(qv1); sA[1][j1] = tanf_(ql1); sA[2][j1] = tanf_(qu1); }
    else    { sA[0][j1] = sigf(qv1);  sA[1][j1] = sigf(ql1);  sA[2][j1] = sigf(qu1); }
    __syncthreads();
    if (tid < NH) {
      const int hh = tid;
      float iv = sA[0][hh],      il = sA[1][hh],      iu = sA[2][hh];
      float fv = sA[0][NH+hh],   fl = sA[1][NH+hh],   fu = sA[2][NH+hh];
      float gv = sA[0][2*NH+hh], gl = sA[1][2*NH+hh], gu = sA[2][2*NH+hh];
      float ov = sA[0][3*NH+hh], ol = sA[1][3*NH+hh], ou = sA[2][3*NH+hh];
      float cv = sC[0][hh], cl = sC[1][hh], cu = sC[2][hh];
      float p0 = fl*cl, p1 = fl*cu, p2 = fu*cl, p3 = fu*cu;
      float fcl = fminf(fminf(p0,p1), fminf(p2,p3));
      float fcu = fmaxf(fmaxf(p0,p1), fmaxf(p2,p3));
      float fcv = fv*cv;
      p0 = il*gl; p1 = il*gu; p2 = iu*gl; p3 = iu*gu;
      float igl = fminf(fminf(p0,p1), fminf(p2,p3));
      float igu = fmaxf(fmaxf(p0,p1), fmaxf(p2,p3));
      float igv = iv*gv;
      float ncv = fcv + igv, ncl = fcl + igl, ncu = fcu + igu;
      sC[0][hh] = ncv; sC[1][hh] = ncl; sC[2][hh] = ncu;
      float tv = tanf_(ncv), tl = tanf_(ncl), tu = tanf_(ncu);
      float hvn = ov*tv;
      p0 = ol*tl; p1 = ol*tu; p2 = ou*tl; p3 = ou*tu;
      float hl = fminf(fminf(p0,p1), fminf(p2,p3));
      float hu = fmaxf(fmaxf(p0,p1), fmaxf(p2,p3));
      outb[t*NH + hh] = hvn;
      outb[(size_t)NBT*NH + t*NH + hh] = hl;
      outb[2*(size_t)NBT*NH + t*NH + hh] = hu;
      sHV[hh] = __float2half(hvn);
      sHM[hh] = __float2half(0.5f*(hl+hu));
      sHR[hh] = __float2half(0.5f*(hu-hl));
    }
    __syncthreads();
  }
}

extern "C" void kernel_launch(void* const* d_in, const int* in_sizes, int n_in,
                              void* d_out, int out_size, void* d_ws, size_t ws_size,
                              hipStream_t stream) {
  const float* xv   = (const float*)d_in[0];
  const float* xl   = (const float*)d_in[1];
  const float* xu   = (const float*)d_in[2];
  const float* Wih  = (const float*)d_in[3];
  const float* Whh  = (const float*)d_in[4];
  const float* bias = (const float*)d_in[5];
  float* out = (float*)d_out;
  char* ws = (char*)d_ws;
  uint4*  WqHH = (uint4*)ws;                  // 512 KiB
  uint4*  WqIH = (uint4*)(ws + 512 * 1024);   // 256 KiB
  __half* px   = (__half*)(ws + 768 * 1024);  // 3 * 32768 * 1024 * 2B = 201.3 MB

  conv_w_kernel<<<192, 256, 0, stream>>>(Whh, Wih, WqHH, WqIH);
  px_kernel<<<NBT / 32, 512, 0, stream>>>(xv, xl, xu, WqIH, px);
  lstm_kernel<<<NB, 512, 0, stream>>>(WqHH, px, bias, out);
}